// Round 1
// baseline (108.642 us; speedup 1.0000x reference)
//
#include <hip/hip_runtime.h>
#include <math.h>
#include <stdint.h>

#define RESO 128
#define NUM_FEAT 16
#define DATA_DIM 16
#define MLP_W 128
#define NFREQ 4
#define PE_DIM 24
#define IN_DIM 40
#define BATCH 1024
#define N_INTR 443
#define NS 442
#define NTHREADS 448
static __device__ __forceinline__ float rad() { return 1.3f; }
#define STEPF ((float)(1.3 / 128.0))

// ---------------- Morton ----------------
static __device__ __forceinline__ uint32_t expand_bits(uint32_t v) {
    v = (v * 65537u) & 4278190335u;
    v = (v * 257u)   & 251719695u;
    v = (v * 17u)    & 3272356035u;
    v = (v * 5u)     & 1227133513u;
    return v;
}
static __device__ __forceinline__ uint32_t morton3d(uint32_t x, uint32_t y, uint32_t z) {
    return expand_bits(x) | (expand_bits(y) << 1) | (expand_bits(z) << 2);
}

// ---------------- Pre-pass: per-voxel argmax over 16 features ----------------
__global__ __launch_bounds__(256) void vq_argmax_kernel(const float* __restrict__ grid,
                                                        unsigned char* __restrict__ vq) {
    int v = blockIdx.x * blockDim.x + threadIdx.x;
    if (v >= RESO * RESO * RESO) return;
    const float4* g = (const float4*)(grid + (size_t)v * 16);
    float4 a = g[0], b = g[1], c = g[2], d = g[3];
    float vals[16] = {a.x, a.y, a.z, a.w, b.x, b.y, b.z, b.w,
                      c.x, c.y, c.z, c.w, d.x, d.y, d.z, d.w};
    float best = vals[0];
    int bi = 0;
#pragma unroll
    for (int j = 1; j < 16; ++j) {
        if (vals[j] > best) { best = vals[j]; bi = j; }
    }
    vq[v] = (unsigned char)bi;
}

// ---------------- Main: one block per ray ----------------
__global__ __launch_bounds__(NTHREADS) void nerf_main_kernel(
    const float* __restrict__ rays_o, const float* __restrict__ rays_d,
    const float* __restrict__ cbg, const float* __restrict__ W1g,
    const float* __restrict__ b1g, const float* __restrict__ W2g,
    const float* __restrict__ b2g, const unsigned char* __restrict__ vq,
    float* __restrict__ out_rgb, float* __restrict__ out_alpha) {

    __shared__ float W1t[MLP_W * IN_DIM];   // transposed: W1t[o*40 + i] = W1[i,o]
    __shared__ float W2s[MLP_W * 4];
    __shared__ float b1s[MLP_W];
    __shared__ float cbs[NUM_FEAT * DATA_DIM];
    __shared__ float ls[NTHREADS];
    __shared__ float wred[7][4];

    const int b = blockIdx.x;
    const int t = threadIdx.x;

    // stage weights to LDS
    for (int k = t; k < MLP_W * IN_DIM; k += NTHREADS) {
        int o = k / IN_DIM;
        int i = k - o * IN_DIM;
        W1t[k] = W1g[i * MLP_W + o];
    }
    for (int k = t; k < MLP_W * 4; k += NTHREADS) W2s[k] = W2g[k];
    if (t < MLP_W) b1s[t] = b1g[t];
    if (t < NUM_FEAT * DATA_DIM) cbs[t] = cbg[t];

    // per-ray setup (redundant per thread; broadcast loads)
    const float o0 = rays_o[b * 3 + 0], o1 = rays_o[b * 3 + 1], o2 = rays_o[b * 3 + 2];
    const float d0 = rays_d[b * 3 + 0], d1 = rays_d[b * 3 + 1], d2 = rays_d[b * 3 + 2];
    const float R = rad();
    float sd0 = (fabsf(d0) < 1e-8f) ? 1e-8f : d0;
    float sd1 = (fabsf(d1) < 1e-8f) ? 1e-8f : d1;
    float sd2 = (fabsf(d2) < 1e-8f) ? 1e-8f : d2;
    float ta0 = (-R - o0) / sd0, tb0 = (R - o0) / sd0;
    float ta1 = (-R - o1) / sd1, tb1 = (R - o1) / sd1;
    float ta2 = (-R - o2) / sd2, tb2 = (R - o2) / sd2;
    float tmin = fmaxf(fmaxf(fminf(ta0, tb0), fminf(ta1, tb1)), fminf(ta2, tb2));
    float tmax = fminf(fminf(fmaxf(ta0, tb0), fmaxf(ta1, tb1)), fmaxf(ta2, tb2));
    float tnear = fmaxf(tmin, 0.0f);
    float nrm = sqrtf(d0 * d0 + d1 * d1 + d2 * d2);

    __syncthreads();

    float alpha = 0.0f, c0 = 0.0f, c1 = 0.0f, c2 = 0.0f;
    const int s = t;
    const bool lane_active = (s < NS);

    if (lane_active) {
        float i0 = tnear + (float)s * STEPF;
        float i1 = tnear + (float)(s + 1) * STEPF;
        float tm = 0.5f * (i0 + i1);
        float delta = (i1 - i0) * nrm;
        float px = o0 + d0 * tm, py = o1 + d1 * tm, pz = o2 + d2 * tm;
        bool m = (tm < tmax) && (fabsf(px) <= R) && (fabsf(py) <= R) && (fabsf(pz) <= R);
        if (m) {
            // grid coords
            float gx = (px / R + 1.0f) * (RESO * 0.5f);
            float gy = (py / R + 1.0f) * (RESO * 0.5f);
            float gz = (pz / R + 1.0f) * (RESO * 0.5f);
            float flx = floorf(gx), fly = floorf(gy), flz = floorf(gz);
            float ox = gx - flx, oy = gy - fly, oz = gz - flz;
            int ix = (int)flx, iy = (int)fly, iz = (int)flz;

            uint32_t midx[8];
            float wn[8];
#pragma unroll
            for (int n = 0; n < 8; ++n) {
                int bx = (n >> 2) & 1, by = (n >> 1) & 1, bz = n & 1;
                int cx = min(max(ix + bx, 0), RESO - 1);
                int cy = min(max(iy + by, 0), RESO - 1);
                int cz = min(max(iz + bz, 0), RESO - 1);
                midx[n] = morton3d((uint32_t)cx, (uint32_t)cy, (uint32_t)cz);
                wn[n] = (bx ? ox : 1.0f - ox) * (by ? oy : 1.0f - oy) * (bz ? oz : 1.0f - oz);
            }
            int fidx[8];
#pragma unroll
            for (int n = 0; n < 8; ++n) fidx[n] = (int)vq[midx[n]];

            float x[IN_DIM];
#pragma unroll
            for (int j = 0; j < DATA_DIM; ++j) x[j] = 0.0f;
#pragma unroll
            for (int n = 0; n < 8; ++n) {
                const float* cbr = &cbs[fidx[n] * DATA_DIM];
                float wv = wn[n];
#pragma unroll
                for (int j = 0; j < DATA_DIM; ++j) x[j] = fmaf(wv, cbr[j], x[j]);
            }
            // positional encoding of direction: [sin(d*2^f) x3, cos(d*2^f) x3] per f
#pragma unroll
            for (int f = 0; f < NFREQ; ++f) {
                float fr = (float)(1 << f);
                x[16 + f * 6 + 0] = __sinf(d0 * fr);
                x[16 + f * 6 + 1] = __sinf(d1 * fr);
                x[16 + f * 6 + 2] = __sinf(d2 * fr);
                x[16 + f * 6 + 3] = __cosf(d0 * fr);
                x[16 + f * 6 + 4] = __cosf(d1 * fr);
                x[16 + f * 6 + 5] = __cosf(d2 * fr);
            }
            // MLP: 40 -> 128 (relu) -> 4, fused
            float p0 = b2g[0], p1 = b2g[1], p2 = b2g[2], p3 = b2g[3];
            for (int o = 0; o < MLP_W; ++o) {
                float acc = b1s[o];
                const float4* wr = (const float4*)&W1t[o * IN_DIM];
#pragma unroll
                for (int q = 0; q < IN_DIM / 4; ++q) {
                    float4 w4 = wr[q];
                    acc = fmaf(x[4 * q + 0], w4.x, acc);
                    acc = fmaf(x[4 * q + 1], w4.y, acc);
                    acc = fmaf(x[4 * q + 2], w4.z, acc);
                    acc = fmaf(x[4 * q + 3], w4.w, acc);
                }
                float h = fmaxf(acc, 0.0f);
                float4 w2 = *(const float4*)&W2s[o * 4];
                p0 = fmaf(h, w2.x, p0);
                p1 = fmaf(h, w2.y, p1);
                p2 = fmaf(h, w2.z, p2);
                p3 = fmaf(h, w2.w, p3);
            }
            float dens = fmaxf(p0, 0.0f);
            alpha = 1.0f - __expf(-dens * delta);
            c0 = 1.0f / (1.0f + __expf(-p1));
            c1 = 1.0f / (1.0f + __expf(-p2));
            c2 = 1.0f / (1.0f + __expf(-p3));
        }
    }

    // ---- compositing: exclusive cumprod of (1 - alpha + 1e-10) over samples ----
    ls[t] = 1.0f - alpha + 1e-10f;
    __syncthreads();
    for (int off = 1; off < NTHREADS; off <<= 1) {
        float v = ls[t];
        if (t >= off) v *= ls[t - off];
        __syncthreads();
        ls[t] = v;
        __syncthreads();
    }
    float T = (t == 0) ? 1.0f : ls[t - 1];
    float w = alpha * T;
    float a0 = w * c0, a1 = w * c1, a2 = w * c2, a3 = w;

    // wave reduce (wave64)
#pragma unroll
    for (int off = 32; off >= 1; off >>= 1) {
        a0 += __shfl_down(a0, off, 64);
        a1 += __shfl_down(a1, off, 64);
        a2 += __shfl_down(a2, off, 64);
        a3 += __shfl_down(a3, off, 64);
    }
    int wid = t >> 6, lane = t & 63;
    if (lane == 0) { wred[wid][0] = a0; wred[wid][1] = a1; wred[wid][2] = a2; wred[wid][3] = a3; }
    __syncthreads();
    if (t == 0) {
        float r0 = 0, r1 = 0, r2 = 0, rw = 0;
#pragma unroll
        for (int i = 0; i < 7; ++i) {
            r0 += wred[i][0]; r1 += wred[i][1]; r2 += wred[i][2]; rw += wred[i][3];
        }
        float bg = 1.0f - rw;
        out_rgb[b * 3 + 0] = r0 + bg;
        out_rgb[b * 3 + 1] = r1 + bg;
        out_rgb[b * 3 + 2] = r2 + bg;
    }
    if (lane_active) out_alpha[b * NS + s] = alpha;
}

extern "C" void kernel_launch(void* const* d_in, const int* in_sizes, int n_in,
                              void* d_out, int out_size, void* d_ws, size_t ws_size,
                              hipStream_t stream) {
    const float* rays_o   = (const float*)d_in[0];
    const float* rays_d   = (const float*)d_in[1];
    const float* grid     = (const float*)d_in[2];
    const float* codebook = (const float*)d_in[3];
    const float* W1       = (const float*)d_in[4];
    const float* b1       = (const float*)d_in[5];
    const float* W2       = (const float*)d_in[6];
    const float* b2       = (const float*)d_in[7];
    float* out = (float*)d_out;

    unsigned char* vq = (unsigned char*)d_ws;  // 128^3 = 2 MB

    vq_argmax_kernel<<<(RESO * RESO * RESO) / 256, 256, 0, stream>>>(grid, vq);
    nerf_main_kernel<<<BATCH, NTHREADS, 0, stream>>>(
        rays_o, rays_d, codebook, W1, b1, W2, b2, vq,
        out /* rgb: 1024*3 */, out + BATCH * 3 /* alpha: 1024*442 */);
}

// Round 2
// 70.499 us; speedup vs baseline: 1.5410x; 1.5410x over previous
//
#include <hip/hip_runtime.h>
#include <math.h>
#include <stdint.h>

#define RESO 128
#define NUM_FEAT 16
#define DATA_DIM 16
#define MLP_W 128
#define NFREQ 4
#define IN_DIM 40
#define BATCH 1024
#define NS 442
#define NTHREADS 448
#define STEPF ((float)(1.3 / 128.0))

// ---------------- Morton ----------------
static __device__ __forceinline__ uint32_t expand_bits(uint32_t v) {
    v = (v * 65537u) & 4278190335u;
    v = (v * 257u)   & 251719695u;
    v = (v * 17u)    & 3272356035u;
    v = (v * 5u)     & 1227133513u;
    return v;
}
static __device__ __forceinline__ uint32_t morton3d(uint32_t x, uint32_t y, uint32_t z) {
    return expand_bits(x) | (expand_bits(y) << 1) | (expand_bits(z) << 2);
}

// ---------------- Pre-pass 1: per-voxel argmax over 16 features ----------------
__global__ __launch_bounds__(256) void vq_argmax_kernel(const float* __restrict__ grid,
                                                        unsigned char* __restrict__ vq) {
    int v = blockIdx.x * blockDim.x + threadIdx.x;
    if (v >= RESO * RESO * RESO) return;
    const float4* g = (const float4*)(grid + (size_t)v * 16);
    float4 a = g[0], b = g[1], c = g[2], d = g[3];
    float vals[16] = {a.x, a.y, a.z, a.w, b.x, b.y, b.z, b.w,
                      c.x, c.y, c.z, c.w, d.x, d.y, d.z, d.w};
    float best = vals[0];
    int bi = 0;
#pragma unroll
    for (int j = 1; j < 16; ++j) {
        if (vals[j] > best) { best = vals[j]; bi = j; }
    }
    vq[v] = (unsigned char)bi;
}

// ---------------- Pre-pass 2: transpose data-part of W1 -> [128][16] ----------------
__global__ __launch_bounds__(128) void w1_prep_kernel(const float* __restrict__ W1,
                                                      float* __restrict__ W1dT) {
    int o = threadIdx.x;  // 0..127
#pragma unroll
    for (int j = 0; j < DATA_DIM; ++j) W1dT[o * DATA_DIM + j] = W1[j * MLP_W + o];
}

// ---------------- Main: one block per ray ----------------
__global__ __launch_bounds__(NTHREADS) void nerf_main_kernel(
    const float* __restrict__ rays_o, const float* __restrict__ rays_d,
    const float* __restrict__ cbg, const float* __restrict__ W1g,
    const float* __restrict__ b1g, const float* __restrict__ W2g,
    const float* __restrict__ b2g, const unsigned char* __restrict__ vq,
    const float* __restrict__ W1dT,
    float* __restrict__ out_rgb, float* __restrict__ out_alpha) {

    __shared__ __align__(16) float cbs[NUM_FEAT * DATA_DIM];
    __shared__ float pe_b1s[MLP_W];   // b1[o] + pe . W1[16:40, o]  (per-ray constant)
    __shared__ float ls[NTHREADS];
    __shared__ float wred[7][4];

    const int b = blockIdx.x;
    const int t = threadIdx.x;

    // per-ray setup (redundant per thread; broadcast loads)
    const float o0 = rays_o[b * 3 + 0], o1 = rays_o[b * 3 + 1], o2 = rays_o[b * 3 + 2];
    const float d0 = rays_d[b * 3 + 0], d1 = rays_d[b * 3 + 1], d2 = rays_d[b * 3 + 2];
    const float R = 1.3f;
    float sd0 = (fabsf(d0) < 1e-8f) ? 1e-8f : d0;
    float sd1 = (fabsf(d1) < 1e-8f) ? 1e-8f : d1;
    float sd2 = (fabsf(d2) < 1e-8f) ? 1e-8f : d2;
    float ta0 = (-R - o0) / sd0, tb0 = (R - o0) / sd0;
    float ta1 = (-R - o1) / sd1, tb1 = (R - o1) / sd1;
    float ta2 = (-R - o2) / sd2, tb2 = (R - o2) / sd2;
    float tmin = fmaxf(fmaxf(fminf(ta0, tb0), fminf(ta1, tb1)), fminf(ta2, tb2));
    float tmax = fminf(fminf(fmaxf(ta0, tb0), fmaxf(ta1, tb1)), fmaxf(ta2, tb2));
    float tnear = fmaxf(tmin, 0.0f);
    float nrm = sqrtf(d0 * d0 + d1 * d1 + d2 * d2);

    // stage codebook
    if (t < NUM_FEAT * DATA_DIM) cbs[t] = cbg[t];

    // fold positional encoding + b1 into a per-ray bias vector (once per block)
    if (t < MLP_W) {
        float pe[24];
#pragma unroll
        for (int f = 0; f < NFREQ; ++f) {
            float fr = (float)(1 << f);
            pe[f * 6 + 0] = __sinf(d0 * fr);
            pe[f * 6 + 1] = __sinf(d1 * fr);
            pe[f * 6 + 2] = __sinf(d2 * fr);
            pe[f * 6 + 3] = __cosf(d0 * fr);
            pe[f * 6 + 4] = __cosf(d1 * fr);
            pe[f * 6 + 5] = __cosf(d2 * fr);
        }
        float acc = b1g[t];
#pragma unroll
        for (int i = 0; i < 24; ++i)
            acc = fmaf(pe[i], W1g[(DATA_DIM + i) * MLP_W + t], acc);  // coalesced over t
        pe_b1s[t] = acc;
    }
    __syncthreads();

    float alpha = 0.0f, c0 = 0.0f, c1 = 0.0f, c2 = 0.0f;
    const int s = t;
    const bool lane_active = (s < NS);

    float i0 = tnear + (float)s * STEPF;
    float i1 = tnear + (float)(s + 1) * STEPF;
    float tm = 0.5f * (i0 + i1);
    float delta = (i1 - i0) * nrm;
    float px = o0 + d0 * tm, py = o1 + d1 * tm, pz = o2 + d2 * tm;
    bool m = lane_active && (tm < tmax) && (fabsf(px) <= R) && (fabsf(py) <= R) && (fabsf(pz) <= R);

    // interpolated data feature (16 dims), zero for masked lanes
    float x[DATA_DIM];
#pragma unroll
    for (int j = 0; j < DATA_DIM; ++j) x[j] = 0.0f;

    if (m) {
        float gx = (px / R + 1.0f) * (RESO * 0.5f);
        float gy = (py / R + 1.0f) * (RESO * 0.5f);
        float gz = (pz / R + 1.0f) * (RESO * 0.5f);
        float flx = floorf(gx), fly = floorf(gy), flz = floorf(gz);
        float ox = gx - flx, oy = gy - fly, oz = gz - flz;
        int ix = (int)flx, iy = (int)fly, iz = (int)flz;

        uint32_t midx[8];
        float wn[8];
#pragma unroll
        for (int n = 0; n < 8; ++n) {
            int bx = (n >> 2) & 1, by = (n >> 1) & 1, bz = n & 1;
            int cx = min(max(ix + bx, 0), RESO - 1);
            int cy = min(max(iy + by, 0), RESO - 1);
            int cz = min(max(iz + bz, 0), RESO - 1);
            midx[n] = morton3d((uint32_t)cx, (uint32_t)cy, (uint32_t)cz);
            wn[n] = (bx ? ox : 1.0f - ox) * (by ? oy : 1.0f - oy) * (bz ? oz : 1.0f - oz);
        }
#pragma unroll
        for (int n = 0; n < 8; ++n) {
            int fi = (int)vq[midx[n]];
            const float4* cbr = (const float4*)&cbs[fi * DATA_DIM];
            float4 ca = cbr[0], cb4 = cbr[1], cc = cbr[2], cd = cbr[3];
            float wv = wn[n];
            x[0]  = fmaf(wv, ca.x,  x[0]);  x[1]  = fmaf(wv, ca.y,  x[1]);
            x[2]  = fmaf(wv, ca.z,  x[2]);  x[3]  = fmaf(wv, ca.w,  x[3]);
            x[4]  = fmaf(wv, cb4.x, x[4]);  x[5]  = fmaf(wv, cb4.y, x[5]);
            x[6]  = fmaf(wv, cb4.z, x[6]);  x[7]  = fmaf(wv, cb4.w, x[7]);
            x[8]  = fmaf(wv, cc.x,  x[8]);  x[9]  = fmaf(wv, cc.y,  x[9]);
            x[10] = fmaf(wv, cc.z,  x[10]); x[11] = fmaf(wv, cc.w,  x[11]);
            x[12] = fmaf(wv, cd.x,  x[12]); x[13] = fmaf(wv, cd.y,  x[13]);
            x[14] = fmaf(wv, cd.z,  x[14]); x[15] = fmaf(wv, cd.w,  x[15]);
        }
    }

    // MLP under a WAVE-UNIFORM guard so weight loads stay scalar (s_load)
    bool wave_go = __any((int)m);
    if (wave_go) {
        float p0 = b2g[0], p1 = b2g[1], p2 = b2g[2], p3 = b2g[3];
#pragma unroll 4
        for (int o = 0; o < MLP_W; ++o) {
            float acc = pe_b1s[o];                                   // LDS broadcast
            const float4* wr = (const float4*)(W1dT + o * DATA_DIM); // uniform -> s_load
            float4 wa = wr[0], wb = wr[1], wc = wr[2], wd = wr[3];
            acc = fmaf(x[0],  wa.x, acc);  acc = fmaf(x[1],  wa.y, acc);
            acc = fmaf(x[2],  wa.z, acc);  acc = fmaf(x[3],  wa.w, acc);
            acc = fmaf(x[4],  wb.x, acc);  acc = fmaf(x[5],  wb.y, acc);
            acc = fmaf(x[6],  wb.z, acc);  acc = fmaf(x[7],  wb.w, acc);
            acc = fmaf(x[8],  wc.x, acc);  acc = fmaf(x[9],  wc.y, acc);
            acc = fmaf(x[10], wc.z, acc);  acc = fmaf(x[11], wc.w, acc);
            acc = fmaf(x[12], wd.x, acc);  acc = fmaf(x[13], wd.y, acc);
            acc = fmaf(x[14], wd.z, acc);  acc = fmaf(x[15], wd.w, acc);
            float h = fmaxf(acc, 0.0f);
            float4 w2 = *(const float4*)(W2g + o * 4);               // uniform -> s_load
            p0 = fmaf(h, w2.x, p0);
            p1 = fmaf(h, w2.y, p1);
            p2 = fmaf(h, w2.z, p2);
            p3 = fmaf(h, w2.w, p3);
        }
        if (m) {
            float dens = fmaxf(p0, 0.0f);
            alpha = 1.0f - __expf(-dens * delta);
            c0 = 1.0f / (1.0f + __expf(-p1));
            c1 = 1.0f / (1.0f + __expf(-p2));
            c2 = 1.0f / (1.0f + __expf(-p3));
        }
    }

    // ---- compositing: exclusive cumprod of (1 - alpha + 1e-10) over samples ----
    ls[t] = 1.0f - alpha + 1e-10f;
    __syncthreads();
    for (int off = 1; off < NTHREADS; off <<= 1) {
        float v = ls[t];
        if (t >= off) v *= ls[t - off];
        __syncthreads();
        ls[t] = v;
        __syncthreads();
    }
    float T = (t == 0) ? 1.0f : ls[t - 1];
    float w = alpha * T;
    float a0 = w * c0, a1 = w * c1, a2 = w * c2, a3 = w;

    // wave reduce (wave64)
#pragma unroll
    for (int off = 32; off >= 1; off >>= 1) {
        a0 += __shfl_down(a0, off, 64);
        a1 += __shfl_down(a1, off, 64);
        a2 += __shfl_down(a2, off, 64);
        a3 += __shfl_down(a3, off, 64);
    }
    int wid = t >> 6, lane = t & 63;
    if (lane == 0) { wred[wid][0] = a0; wred[wid][1] = a1; wred[wid][2] = a2; wred[wid][3] = a3; }
    __syncthreads();
    if (t == 0) {
        float r0 = 0, r1 = 0, r2 = 0, rw = 0;
#pragma unroll
        for (int i = 0; i < 7; ++i) {
            r0 += wred[i][0]; r1 += wred[i][1]; r2 += wred[i][2]; rw += wred[i][3];
        }
        float bg = 1.0f - rw;
        out_rgb[b * 3 + 0] = r0 + bg;
        out_rgb[b * 3 + 1] = r1 + bg;
        out_rgb[b * 3 + 2] = r2 + bg;
    }
    if (lane_active) out_alpha[b * NS + s] = alpha;
}

extern "C" void kernel_launch(void* const* d_in, const int* in_sizes, int n_in,
                              void* d_out, int out_size, void* d_ws, size_t ws_size,
                              hipStream_t stream) {
    const float* rays_o   = (const float*)d_in[0];
    const float* rays_d   = (const float*)d_in[1];
    const float* grid     = (const float*)d_in[2];
    const float* codebook = (const float*)d_in[3];
    const float* W1       = (const float*)d_in[4];
    const float* b1       = (const float*)d_in[5];
    const float* W2       = (const float*)d_in[6];
    const float* b2       = (const float*)d_in[7];
    float* out = (float*)d_out;

    unsigned char* vq = (unsigned char*)d_ws;                    // 128^3 = 2 MB
    float* W1dT = (float*)((char*)d_ws + (2u << 20));            // 128*16 f32 = 8 KB

    vq_argmax_kernel<<<(RESO * RESO * RESO) / 256, 256, 0, stream>>>(grid, vq);
    w1_prep_kernel<<<1, 128, 0, stream>>>(W1, W1dT);
    nerf_main_kernel<<<BATCH, NTHREADS, 0, stream>>>(
        rays_o, rays_d, codebook, W1, b1, W2, b2, vq, W1dT,
        out /* rgb: 1024*3 */, out + BATCH * 3 /* alpha: 1024*442 */);
}

// Round 3
// 57.253 us; speedup vs baseline: 1.8976x; 1.2314x over previous
//
#include <hip/hip_runtime.h>
#include <math.h>
#include <stdint.h>

#define RESO 128
#define NUM_FEAT 16
#define DATA_DIM 16
#define MLP_W 128
#define NFREQ 4
#define BATCH 1024
#define NS 442
#define NT 256
#define NWAVES 4
#define NCHUNK 2
#define STEPF ((float)(1.3 / 128.0))

// ---------------- Morton ----------------
static __device__ __forceinline__ uint32_t expand_bits(uint32_t v) {
    v = (v * 65537u) & 4278190335u;
    v = (v * 257u)   & 251719695u;
    v = (v * 17u)    & 3272356035u;
    v = (v * 5u)     & 1227133513u;
    return v;
}
static __device__ __forceinline__ uint32_t morton3d(uint32_t x, uint32_t y, uint32_t z) {
    return expand_bits(x) | (expand_bits(y) << 1) | (expand_bits(z) << 2);
}

// ------- Pre-pass: per-voxel argmax + (block 0) W1 data-part transpose -------
__global__ __launch_bounds__(256) void vq_argmax_kernel(const float* __restrict__ grid,
                                                        unsigned char* __restrict__ vq,
                                                        const float* __restrict__ W1,
                                                        float* __restrict__ W1dT) {
    int v = blockIdx.x * blockDim.x + threadIdx.x;
    if (v < RESO * RESO * RESO) {
        const float4* g = (const float4*)(grid + (size_t)v * 16);
        float4 a = g[0], b = g[1], c = g[2], d = g[3];
        float vals[16] = {a.x, a.y, a.z, a.w, b.x, b.y, b.z, b.w,
                          c.x, c.y, c.z, c.w, d.x, d.y, d.z, d.w};
        float best = vals[0];
        int bi = 0;
#pragma unroll
        for (int j = 1; j < 16; ++j) {
            if (vals[j] > best) { best = vals[j]; bi = j; }
        }
        vq[v] = (unsigned char)bi;
    }
    if (blockIdx.x == 0 && threadIdx.x < MLP_W) {
        int o = threadIdx.x;
#pragma unroll
        for (int j = 0; j < DATA_DIM; ++j) W1dT[o * DATA_DIM + j] = W1[j * MLP_W + o];
    }
}

// ---------------- Main: one block (256 thr) per ray, 2 chunks ----------------
__global__ __launch_bounds__(NT) void nerf_main_kernel(
    const float* __restrict__ rays_o, const float* __restrict__ rays_d,
    const float* __restrict__ cbg, const float* __restrict__ W1g,
    const float* __restrict__ b1g, const float* __restrict__ W2g,
    const float* __restrict__ b2g, const unsigned char* __restrict__ vq,
    const float* __restrict__ W1dT,
    float* __restrict__ out_rgb, float* __restrict__ out_alpha) {

    __shared__ __align__(16) float cbs[NUM_FEAT * DATA_DIM];
    __shared__ float pe_b1s[MLP_W];         // b1[o] + pe . W1[16:40, o]
    __shared__ float wtot[NCHUNK][NWAVES];  // per-wave transmittance products
    __shared__ float wred[NWAVES][4];

    const int b = blockIdx.x;
    const int t = threadIdx.x;
    const int wid = t >> 6;
    const int lane = t & 63;

    // per-ray setup (broadcast loads)
    const float o0 = rays_o[b * 3 + 0], o1 = rays_o[b * 3 + 1], o2 = rays_o[b * 3 + 2];
    const float d0 = rays_d[b * 3 + 0], d1 = rays_d[b * 3 + 1], d2 = rays_d[b * 3 + 2];
    const float R = 1.3f;
    float sd0 = (fabsf(d0) < 1e-8f) ? 1e-8f : d0;
    float sd1 = (fabsf(d1) < 1e-8f) ? 1e-8f : d1;
    float sd2 = (fabsf(d2) < 1e-8f) ? 1e-8f : d2;
    float ta0 = (-R - o0) / sd0, tb0 = (R - o0) / sd0;
    float ta1 = (-R - o1) / sd1, tb1 = (R - o1) / sd1;
    float ta2 = (-R - o2) / sd2, tb2 = (R - o2) / sd2;
    float tmin = fmaxf(fmaxf(fminf(ta0, tb0), fminf(ta1, tb1)), fminf(ta2, tb2));
    float tmax = fminf(fminf(fmaxf(ta0, tb0), fmaxf(ta1, tb1)), fmaxf(ta2, tb2));
    float tnear = fmaxf(tmin, 0.0f);
    float nrm = sqrtf(d0 * d0 + d1 * d1 + d2 * d2);

    // stage codebook (256 values, one per thread)
    cbs[t] = cbg[t];

    // fold positional encoding + b1 into per-ray bias (once per block)
    if (t < MLP_W) {
        float acc = b1g[t];
#pragma unroll
        for (int f = 0; f < NFREQ; ++f) {
            float fr = (float)(1 << f);
            acc = fmaf(__sinf(d0 * fr), W1g[(DATA_DIM + f * 6 + 0) * MLP_W + t], acc);
            acc = fmaf(__sinf(d1 * fr), W1g[(DATA_DIM + f * 6 + 1) * MLP_W + t], acc);
            acc = fmaf(__sinf(d2 * fr), W1g[(DATA_DIM + f * 6 + 2) * MLP_W + t], acc);
            acc = fmaf(__cosf(d0 * fr), W1g[(DATA_DIM + f * 6 + 3) * MLP_W + t], acc);
            acc = fmaf(__cosf(d1 * fr), W1g[(DATA_DIM + f * 6 + 4) * MLP_W + t], acc);
            acc = fmaf(__cosf(d2 * fr), W1g[(DATA_DIM + f * 6 + 5) * MLP_W + t], acc);
        }
        pe_b1s[t] = acc;
    }
    __syncthreads();

    float carry = 1.0f;                    // block-wide transmittance carry
    float r0 = 0.0f, r1 = 0.0f, r2 = 0.0f, rw = 0.0f;

    for (int chunk = 0; chunk < NCHUNK; ++chunk) {
        const int s = chunk * NT + t;
        const bool lane_active = (s < NS);

        float i0 = tnear + (float)s * STEPF;
        float i1 = tnear + (float)(s + 1) * STEPF;
        float tm = 0.5f * (i0 + i1);
        float delta = (i1 - i0) * nrm;
        float px = o0 + d0 * tm, py = o1 + d1 * tm, pz = o2 + d2 * tm;
        bool m = lane_active && (tm < tmax) &&
                 (fabsf(px) <= R) && (fabsf(py) <= R) && (fabsf(pz) <= R);

        float alpha = 0.0f, c0 = 0.0f, c1 = 0.0f, c2 = 0.0f;

        float x[DATA_DIM];
#pragma unroll
        for (int j = 0; j < DATA_DIM; ++j) x[j] = 0.0f;

        if (m) {
            float gx = (px / R + 1.0f) * (RESO * 0.5f);
            float gy = (py / R + 1.0f) * (RESO * 0.5f);
            float gz = (pz / R + 1.0f) * (RESO * 0.5f);
            float flx = floorf(gx), fly = floorf(gy), flz = floorf(gz);
            float ox = gx - flx, oy = gy - fly, oz = gz - flz;
            int ix = (int)flx, iy = (int)fly, iz = (int)flz;

            uint32_t midx[8];
            float wn[8];
#pragma unroll
            for (int n = 0; n < 8; ++n) {
                int bx = (n >> 2) & 1, by = (n >> 1) & 1, bz = n & 1;
                int cx = min(max(ix + bx, 0), RESO - 1);
                int cy = min(max(iy + by, 0), RESO - 1);
                int cz = min(max(iz + bz, 0), RESO - 1);
                midx[n] = morton3d((uint32_t)cx, (uint32_t)cy, (uint32_t)cz);
                wn[n] = (bx ? ox : 1.0f - ox) * (by ? oy : 1.0f - oy) * (bz ? oz : 1.0f - oz);
            }
#pragma unroll
            for (int n = 0; n < 8; ++n) {
                int fi = (int)vq[midx[n]];
                const float4* cbr = (const float4*)&cbs[fi * DATA_DIM];
                float4 ca = cbr[0], cb4 = cbr[1], cc = cbr[2], cd = cbr[3];
                float wv = wn[n];
                x[0]  = fmaf(wv, ca.x,  x[0]);  x[1]  = fmaf(wv, ca.y,  x[1]);
                x[2]  = fmaf(wv, ca.z,  x[2]);  x[3]  = fmaf(wv, ca.w,  x[3]);
                x[4]  = fmaf(wv, cb4.x, x[4]);  x[5]  = fmaf(wv, cb4.y, x[5]);
                x[6]  = fmaf(wv, cb4.z, x[6]);  x[7]  = fmaf(wv, cb4.w, x[7]);
                x[8]  = fmaf(wv, cc.x,  x[8]);  x[9]  = fmaf(wv, cc.y,  x[9]);
                x[10] = fmaf(wv, cc.z,  x[10]); x[11] = fmaf(wv, cc.w,  x[11]);
                x[12] = fmaf(wv, cd.x,  x[12]); x[13] = fmaf(wv, cd.y,  x[13]);
                x[14] = fmaf(wv, cd.z,  x[14]); x[15] = fmaf(wv, cd.w,  x[15]);
            }
        }

        // MLP under a wave-uniform guard so weight loads stay scalar (s_load)
        if (__any((int)m)) {
            float p0 = b2g[0], p1 = b2g[1], p2 = b2g[2], p3 = b2g[3];
#pragma unroll 4
            for (int o = 0; o < MLP_W; ++o) {
                float acc = pe_b1s[o];                                   // LDS broadcast
                const float4* wr = (const float4*)(W1dT + o * DATA_DIM); // uniform -> s_load
                float4 wa = wr[0], wb = wr[1], wc = wr[2], wd = wr[3];
                acc = fmaf(x[0],  wa.x, acc);  acc = fmaf(x[1],  wa.y, acc);
                acc = fmaf(x[2],  wa.z, acc);  acc = fmaf(x[3],  wa.w, acc);
                acc = fmaf(x[4],  wb.x, acc);  acc = fmaf(x[5],  wb.y, acc);
                acc = fmaf(x[6],  wb.z, acc);  acc = fmaf(x[7],  wb.w, acc);
                acc = fmaf(x[8],  wc.x, acc);  acc = fmaf(x[9],  wc.y, acc);
                acc = fmaf(x[10], wc.z, acc);  acc = fmaf(x[11], wc.w, acc);
                acc = fmaf(x[12], wd.x, acc);  acc = fmaf(x[13], wd.y, acc);
                acc = fmaf(x[14], wd.z, acc);  acc = fmaf(x[15], wd.w, acc);
                float h = fmaxf(acc, 0.0f);
                float4 w2 = *(const float4*)(W2g + o * 4);               // uniform -> s_load
                p0 = fmaf(h, w2.x, p0);
                p1 = fmaf(h, w2.y, p1);
                p2 = fmaf(h, w2.z, p2);
                p3 = fmaf(h, w2.w, p3);
            }
            if (m) {
                float dens = fmaxf(p0, 0.0f);
                alpha = 1.0f - __expf(-dens * delta);
                c0 = 1.0f / (1.0f + __expf(-p1));
                c1 = 1.0f / (1.0f + __expf(-p2));
                c2 = 1.0f / (1.0f + __expf(-p3));
            }
        }

        // ---- compositing: wave64 shuffle product-scan + cross-wave combine ----
        float v = 1.0f - alpha + 1e-10f;
        float inc = v;
#pragma unroll
        for (int off = 1; off < 64; off <<= 1) {
            float u = __shfl_up(inc, off, 64);
            if (lane >= off) inc *= u;
        }
        float excl = __shfl_up(inc, 1, 64);
        if (lane == 0) excl = 1.0f;
        if (lane == 63) wtot[chunk][wid] = inc;   // wave total product
        __syncthreads();

        float wpre = carry;                        // product of carry + preceding waves
#pragma unroll
        for (int w = 0; w < NWAVES; ++w)
            if (w < wid) wpre *= wtot[chunk][w];
        float T = wpre * excl;
        float wgt = alpha * T;
        r0 = fmaf(wgt, c0, r0);
        r1 = fmaf(wgt, c1, r1);
        r2 = fmaf(wgt, c2, r2);
        rw += wgt;

        // update carry with full-block product of this chunk (uniform)
        float allp = wtot[chunk][0] * wtot[chunk][1] * wtot[chunk][2] * wtot[chunk][3];
        carry *= allp;

        if (lane_active) out_alpha[b * NS + s] = alpha;
        // no end-of-loop barrier needed: next chunk writes wtot[chunk+1][*]
    }

    // ---- final rgb reduction ----
#pragma unroll
    for (int off = 32; off >= 1; off >>= 1) {
        r0 += __shfl_down(r0, off, 64);
        r1 += __shfl_down(r1, off, 64);
        r2 += __shfl_down(r2, off, 64);
        rw += __shfl_down(rw, off, 64);
    }
    if (lane == 0) { wred[wid][0] = r0; wred[wid][1] = r1; wred[wid][2] = r2; wred[wid][3] = rw; }
    __syncthreads();
    if (t == 0) {
        float s0 = 0, s1 = 0, s2 = 0, sw = 0;
#pragma unroll
        for (int i = 0; i < NWAVES; ++i) {
            s0 += wred[i][0]; s1 += wred[i][1]; s2 += wred[i][2]; sw += wred[i][3];
        }
        float bg = 1.0f - sw;
        out_rgb[b * 3 + 0] = s0 + bg;
        out_rgb[b * 3 + 1] = s1 + bg;
        out_rgb[b * 3 + 2] = s2 + bg;
    }
}

extern "C" void kernel_launch(void* const* d_in, const int* in_sizes, int n_in,
                              void* d_out, int out_size, void* d_ws, size_t ws_size,
                              hipStream_t stream) {
    const float* rays_o   = (const float*)d_in[0];
    const float* rays_d   = (const float*)d_in[1];
    const float* grid     = (const float*)d_in[2];
    const float* codebook = (const float*)d_in[3];
    const float* W1       = (const float*)d_in[4];
    const float* b1       = (const float*)d_in[5];
    const float* W2       = (const float*)d_in[6];
    const float* b2       = (const float*)d_in[7];
    float* out = (float*)d_out;

    unsigned char* vq = (unsigned char*)d_ws;                    // 128^3 = 2 MB
    float* W1dT = (float*)((char*)d_ws + (2u << 20));            // 128*16 f32 = 8 KB

    vq_argmax_kernel<<<(RESO * RESO * RESO) / 256, 256, 0, stream>>>(grid, vq, W1, W1dT);
    nerf_main_kernel<<<BATCH, NT, 0, stream>>>(
        rays_o, rays_d, codebook, W1, b1, W2, b2, vq, W1dT,
        out /* rgb: 1024*3 */, out + BATCH * 3 /* alpha: 1024*442 */);
}

// Round 4
// 48.375 us; speedup vs baseline: 2.2458x; 1.1835x over previous
//
#include <hip/hip_runtime.h>
#include <math.h>
#include <stdint.h>

#define RESO 128
#define NUM_FEAT 16
#define DATA_DIM 16
#define MLP_W 128
#define NFREQ 4
#define BATCH 1024
#define NS 442
#define NT 256
#define NWAVES 4
#define NCHUNK 2
#define STEPF ((float)(1.3 / 128.0))

// ---------------- Morton ----------------
static __device__ __forceinline__ uint32_t expand_bits(uint32_t v) {
    v = (v * 65537u) & 4278190335u;
    v = (v * 257u)   & 251719695u;
    v = (v * 17u)    & 3272356035u;
    v = (v * 5u)     & 1227133513u;
    return v;
}
static __device__ __forceinline__ uint32_t morton3d(uint32_t x, uint32_t y, uint32_t z) {
    return expand_bits(x) | (expand_bits(y) << 1) | (expand_bits(z) << 2);
}

// ------- Pre-pass: W1 data-part transpose -> [128][16] (tiny) -------
__global__ __launch_bounds__(128) void w1_prep_kernel(const float* __restrict__ W1,
                                                      float* __restrict__ W1dT) {
    int o = threadIdx.x;  // 0..127
#pragma unroll
    for (int j = 0; j < DATA_DIM; ++j) W1dT[o * DATA_DIM + j] = W1[j * MLP_W + o];
}

// ---------------- Main: one block (256 thr) per ray, 2 chunks ----------------
__global__ __launch_bounds__(NT) void nerf_main_kernel(
    const float* __restrict__ rays_o, const float* __restrict__ rays_d,
    const float* __restrict__ grid, const float* __restrict__ cbg,
    const float* __restrict__ W1g, const float* __restrict__ b1g,
    const float* __restrict__ W2g, const float* __restrict__ b2g,
    const float* __restrict__ W1dT,
    float* __restrict__ out_rgb, float* __restrict__ out_alpha) {

    __shared__ __align__(16) float cbs[NUM_FEAT * DATA_DIM];
    __shared__ float pe_b1s[MLP_W];         // b1[o] + pe . W1[16:40, o]
    __shared__ float wtot[NCHUNK][NWAVES];  // per-wave transmittance products
    __shared__ float wred[NWAVES][4];

    const int b = blockIdx.x;
    const int t = threadIdx.x;
    const int wid = t >> 6;
    const int lane = t & 63;

    // per-ray setup (broadcast loads)
    const float o0 = rays_o[b * 3 + 0], o1 = rays_o[b * 3 + 1], o2 = rays_o[b * 3 + 2];
    const float d0 = rays_d[b * 3 + 0], d1 = rays_d[b * 3 + 1], d2 = rays_d[b * 3 + 2];
    const float R = 1.3f;
    float sd0 = (fabsf(d0) < 1e-8f) ? 1e-8f : d0;
    float sd1 = (fabsf(d1) < 1e-8f) ? 1e-8f : d1;
    float sd2 = (fabsf(d2) < 1e-8f) ? 1e-8f : d2;
    float ta0 = (-R - o0) / sd0, tb0 = (R - o0) / sd0;
    float ta1 = (-R - o1) / sd1, tb1 = (R - o1) / sd1;
    float ta2 = (-R - o2) / sd2, tb2 = (R - o2) / sd2;
    float tmin = fmaxf(fmaxf(fminf(ta0, tb0), fminf(ta1, tb1)), fminf(ta2, tb2));
    float tmax = fminf(fminf(fmaxf(ta0, tb0), fmaxf(ta1, tb1)), fmaxf(ta2, tb2));
    float tnear = fmaxf(tmin, 0.0f);
    float nrm = sqrtf(d0 * d0 + d1 * d1 + d2 * d2);

    // stage codebook (256 values, one per thread)
    cbs[t] = cbg[t];

    // fold positional encoding + b1 into per-ray bias (once per block)
    if (t < MLP_W) {
        float acc = b1g[t];
#pragma unroll
        for (int f = 0; f < NFREQ; ++f) {
            float fr = (float)(1 << f);
            acc = fmaf(__sinf(d0 * fr), W1g[(DATA_DIM + f * 6 + 0) * MLP_W + t], acc);
            acc = fmaf(__sinf(d1 * fr), W1g[(DATA_DIM + f * 6 + 1) * MLP_W + t], acc);
            acc = fmaf(__sinf(d2 * fr), W1g[(DATA_DIM + f * 6 + 2) * MLP_W + t], acc);
            acc = fmaf(__cosf(d0 * fr), W1g[(DATA_DIM + f * 6 + 3) * MLP_W + t], acc);
            acc = fmaf(__cosf(d1 * fr), W1g[(DATA_DIM + f * 6 + 4) * MLP_W + t], acc);
            acc = fmaf(__cosf(d2 * fr), W1g[(DATA_DIM + f * 6 + 5) * MLP_W + t], acc);
        }
        pe_b1s[t] = acc;
    }
    __syncthreads();

    float carry = 1.0f;                    // block-wide transmittance carry
    float r0 = 0.0f, r1 = 0.0f, r2 = 0.0f, rw = 0.0f;

    for (int chunk = 0; chunk < NCHUNK; ++chunk) {
        const int s = chunk * NT + t;
        const bool lane_active = (s < NS);

        float i0 = tnear + (float)s * STEPF;
        float i1 = tnear + (float)(s + 1) * STEPF;
        float tm = 0.5f * (i0 + i1);
        float delta = (i1 - i0) * nrm;
        float px = o0 + d0 * tm, py = o1 + d1 * tm, pz = o2 + d2 * tm;
        bool m = lane_active && (tm < tmax) &&
                 (fabsf(px) <= R) && (fabsf(py) <= R) && (fabsf(pz) <= R);

        float alpha = 0.0f, c0 = 0.0f, c1 = 0.0f, c2 = 0.0f;

        float x[DATA_DIM];
#pragma unroll
        for (int j = 0; j < DATA_DIM; ++j) x[j] = 0.0f;

        if (m) {
            float gx = (px / R + 1.0f) * (RESO * 0.5f);
            float gy = (py / R + 1.0f) * (RESO * 0.5f);
            float gz = (pz / R + 1.0f) * (RESO * 0.5f);
            float flx = floorf(gx), fly = floorf(gy), flz = floorf(gz);
            float ox = gx - flx, oy = gy - fly, oz = gz - flz;
            int ix = (int)flx, iy = (int)fly, iz = (int)flz;

#pragma unroll
            for (int n = 0; n < 8; ++n) {
                int bx = (n >> 2) & 1, by = (n >> 1) & 1, bz = n & 1;
                int cx = min(max(ix + bx, 0), RESO - 1);
                int cy = min(max(iy + by, 0), RESO - 1);
                int cz = min(max(iz + bz, 0), RESO - 1);
                uint32_t mi = morton3d((uint32_t)cx, (uint32_t)cy, (uint32_t)cz);
                float wv = (bx ? ox : 1.0f - ox) * (by ? oy : 1.0f - oy) * (bz ? oz : 1.0f - oz);

                // on-demand VQ: argmax of grid[mi, 0..15] (first-max-wins)
                const float4* g4 = (const float4*)(grid + ((size_t)mi << 4));
                float4 A = g4[0], B = g4[1], C = g4[2], D = g4[3];
                float v[16] = {A.x, A.y, A.z, A.w, B.x, B.y, B.z, B.w,
                               C.x, C.y, C.z, C.w, D.x, D.y, D.z, D.w};
                float bestv = v[0];
                int bi = 0;
#pragma unroll
                for (int j = 1; j < 16; ++j) {
                    bi = (v[j] > bestv) ? j : bi;
                    bestv = fmaxf(v[j], bestv);
                }

                const float4* cbr = (const float4*)&cbs[bi * DATA_DIM];
                float4 ca = cbr[0], cb4 = cbr[1], cc = cbr[2], cd = cbr[3];
                x[0]  = fmaf(wv, ca.x,  x[0]);  x[1]  = fmaf(wv, ca.y,  x[1]);
                x[2]  = fmaf(wv, ca.z,  x[2]);  x[3]  = fmaf(wv, ca.w,  x[3]);
                x[4]  = fmaf(wv, cb4.x, x[4]);  x[5]  = fmaf(wv, cb4.y, x[5]);
                x[6]  = fmaf(wv, cb4.z, x[6]);  x[7]  = fmaf(wv, cb4.w, x[7]);
                x[8]  = fmaf(wv, cc.x,  x[8]);  x[9]  = fmaf(wv, cc.y,  x[9]);
                x[10] = fmaf(wv, cc.z,  x[10]); x[11] = fmaf(wv, cc.w,  x[11]);
                x[12] = fmaf(wv, cd.x,  x[12]); x[13] = fmaf(wv, cd.y,  x[13]);
                x[14] = fmaf(wv, cd.z,  x[14]); x[15] = fmaf(wv, cd.w,  x[15]);
            }
        }

        // MLP under a wave-uniform guard so weight loads stay scalar (s_load)
        if (__any((int)m)) {
            float p0 = b2g[0], p1 = b2g[1], p2 = b2g[2], p3 = b2g[3];
#pragma unroll 4
            for (int o = 0; o < MLP_W; ++o) {
                float acc = pe_b1s[o];                                   // LDS broadcast
                const float4* wr = (const float4*)(W1dT + o * DATA_DIM); // uniform -> s_load
                float4 wa = wr[0], wb = wr[1], wc = wr[2], wd = wr[3];
                acc = fmaf(x[0],  wa.x, acc);  acc = fmaf(x[1],  wa.y, acc);
                acc = fmaf(x[2],  wa.z, acc);  acc = fmaf(x[3],  wa.w, acc);
                acc = fmaf(x[4],  wb.x, acc);  acc = fmaf(x[5],  wb.y, acc);
                acc = fmaf(x[6],  wb.z, acc);  acc = fmaf(x[7],  wb.w, acc);
                acc = fmaf(x[8],  wc.x, acc);  acc = fmaf(x[9],  wc.y, acc);
                acc = fmaf(x[10], wc.z, acc);  acc = fmaf(x[11], wc.w, acc);
                acc = fmaf(x[12], wd.x, acc);  acc = fmaf(x[13], wd.y, acc);
                acc = fmaf(x[14], wd.z, acc);  acc = fmaf(x[15], wd.w, acc);
                float h = fmaxf(acc, 0.0f);
                float4 w2 = *(const float4*)(W2g + o * 4);               // uniform -> s_load
                p0 = fmaf(h, w2.x, p0);
                p1 = fmaf(h, w2.y, p1);
                p2 = fmaf(h, w2.z, p2);
                p3 = fmaf(h, w2.w, p3);
            }
            if (m) {
                float dens = fmaxf(p0, 0.0f);
                alpha = 1.0f - __expf(-dens * delta);
                c0 = 1.0f / (1.0f + __expf(-p1));
                c1 = 1.0f / (1.0f + __expf(-p2));
                c2 = 1.0f / (1.0f + __expf(-p3));
            }
        }

        // ---- compositing: wave64 shuffle product-scan + cross-wave combine ----
        float v = 1.0f - alpha + 1e-10f;
        float inc = v;
#pragma unroll
        for (int off = 1; off < 64; off <<= 1) {
            float u = __shfl_up(inc, off, 64);
            if (lane >= off) inc *= u;
        }
        float excl = __shfl_up(inc, 1, 64);
        if (lane == 0) excl = 1.0f;
        if (lane == 63) wtot[chunk][wid] = inc;   // wave total product
        __syncthreads();

        float wpre = carry;                        // product of carry + preceding waves
#pragma unroll
        for (int w = 0; w < NWAVES; ++w)
            if (w < wid) wpre *= wtot[chunk][w];
        float T = wpre * excl;
        float wgt = alpha * T;
        r0 = fmaf(wgt, c0, r0);
        r1 = fmaf(wgt, c1, r1);
        r2 = fmaf(wgt, c2, r2);
        rw += wgt;

        // update carry with full-block product of this chunk (uniform)
        float allp = wtot[chunk][0] * wtot[chunk][1] * wtot[chunk][2] * wtot[chunk][3];
        carry *= allp;

        if (lane_active) out_alpha[b * NS + s] = alpha;
    }

    // ---- final rgb reduction ----
#pragma unroll
    for (int off = 32; off >= 1; off >>= 1) {
        r0 += __shfl_down(r0, off, 64);
        r1 += __shfl_down(r1, off, 64);
        r2 += __shfl_down(r2, off, 64);
        rw += __shfl_down(rw, off, 64);
    }
    if (lane == 0) { wred[wid][0] = r0; wred[wid][1] = r1; wred[wid][2] = r2; wred[wid][3] = rw; }
    __syncthreads();
    if (t == 0) {
        float s0 = 0, s1 = 0, s2 = 0, sw = 0;
#pragma unroll
        for (int i = 0; i < NWAVES; ++i) {
            s0 += wred[i][0]; s1 += wred[i][1]; s2 += wred[i][2]; sw += wred[i][3];
        }
        float bg = 1.0f - sw;
        out_rgb[b * 3 + 0] = s0 + bg;
        out_rgb[b * 3 + 1] = s1 + bg;
        out_rgb[b * 3 + 2] = s2 + bg;
    }
}

extern "C" void kernel_launch(void* const* d_in, const int* in_sizes, int n_in,
                              void* d_out, int out_size, void* d_ws, size_t ws_size,
                              hipStream_t stream) {
    const float* rays_o   = (const float*)d_in[0];
    const float* rays_d   = (const float*)d_in[1];
    const float* grid     = (const float*)d_in[2];
    const float* codebook = (const float*)d_in[3];
    const float* W1       = (const float*)d_in[4];
    const float* b1       = (const float*)d_in[5];
    const float* W2       = (const float*)d_in[6];
    const float* b2       = (const float*)d_in[7];
    float* out = (float*)d_out;

    float* W1dT = (float*)d_ws;   // 128*16 f32 = 8 KB

    w1_prep_kernel<<<1, 128, 0, stream>>>(W1, W1dT);
    nerf_main_kernel<<<BATCH, NT, 0, stream>>>(
        rays_o, rays_d, grid, codebook, W1, b1, W2, b2, W1dT,
        out /* rgb: 1024*3 */, out + BATCH * 3 /* alpha: 1024*442 */);
}

// Round 5
// 46.574 us; speedup vs baseline: 2.3327x; 1.0387x over previous
//
#include <hip/hip_runtime.h>
#include <math.h>
#include <stdint.h>

#define RESO 128
#define NUM_FEAT 16
#define DATA_DIM 16
#define MLP_W 128
#define NFREQ 4
#define BATCH 1024
#define NS 442
#define NT 512
#define NWAVES 8
#define STEPF ((float)(1.3 / 128.0))

// ---------------- Morton ----------------
static __device__ __forceinline__ uint32_t expand_bits(uint32_t v) {
    v = (v * 65537u) & 4278190335u;
    v = (v * 257u)   & 251719695u;
    v = (v * 17u)    & 3272356035u;
    v = (v * 5u)     & 1227133513u;
    return v;
}
static __device__ __forceinline__ uint32_t morton3d(uint32_t x, uint32_t y, uint32_t z) {
    return expand_bits(x) | (expand_bits(y) << 1) | (expand_bits(z) << 2);
}

// ------- Pre-pass: W1 data-part transpose -> [128][16] (tiny) -------
__global__ __launch_bounds__(128) void w1_prep_kernel(const float* __restrict__ W1,
                                                      float* __restrict__ W1dT) {
    int o = threadIdx.x;  // 0..127
#pragma unroll
    for (int j = 0; j < DATA_DIM; ++j) W1dT[o * DATA_DIM + j] = W1[j * MLP_W + o];
}

// ---------------- Main: one block (512 thr, 8 waves) per ray ----------------
__global__ __launch_bounds__(NT) void nerf_main_kernel(
    const float* __restrict__ rays_o, const float* __restrict__ rays_d,
    const float* __restrict__ grid, const float* __restrict__ cbg,
    const float* __restrict__ W1g, const float* __restrict__ b1g,
    const float* __restrict__ W2g, const float* __restrict__ b2g,
    const float* __restrict__ W1dT,
    float* __restrict__ out_rgb, float* __restrict__ out_alpha) {

    __shared__ __align__(16) float cbs[NUM_FEAT * DATA_DIM];
    __shared__ float pe_b1s[MLP_W];     // b1[o] + pe . W1[16:40, o]
    __shared__ float wtot[NWAVES];      // per-wave transmittance products
    __shared__ float wred[NWAVES][4];

    const int b = blockIdx.x;
    const int t = threadIdx.x;
    const int wid = t >> 6;
    const int lane = t & 63;

    // per-ray setup (broadcast loads)
    const float o0 = rays_o[b * 3 + 0], o1 = rays_o[b * 3 + 1], o2 = rays_o[b * 3 + 2];
    const float d0 = rays_d[b * 3 + 0], d1 = rays_d[b * 3 + 1], d2 = rays_d[b * 3 + 2];
    const float R = 1.3f;
    float sd0 = (fabsf(d0) < 1e-8f) ? 1e-8f : d0;
    float sd1 = (fabsf(d1) < 1e-8f) ? 1e-8f : d1;
    float sd2 = (fabsf(d2) < 1e-8f) ? 1e-8f : d2;
    float ta0 = (-R - o0) / sd0, tb0 = (R - o0) / sd0;
    float ta1 = (-R - o1) / sd1, tb1 = (R - o1) / sd1;
    float ta2 = (-R - o2) / sd2, tb2 = (R - o2) / sd2;
    float tmin = fmaxf(fmaxf(fminf(ta0, tb0), fminf(ta1, tb1)), fminf(ta2, tb2));
    float tmax = fminf(fminf(fmaxf(ta0, tb0), fmaxf(ta1, tb1)), fmaxf(ta2, tb2));
    float tnear = fmaxf(tmin, 0.0f);
    float nrm = sqrtf(d0 * d0 + d1 * d1 + d2 * d2);

    // stage codebook (256 values)
    if (t < NUM_FEAT * DATA_DIM) cbs[t] = cbg[t];

    // fold positional encoding + b1 into per-ray bias (once per block)
    if (t < MLP_W) {
        float acc = b1g[t];
#pragma unroll
        for (int f = 0; f < NFREQ; ++f) {
            float fr = (float)(1 << f);
            acc = fmaf(__sinf(d0 * fr), W1g[(DATA_DIM + f * 6 + 0) * MLP_W + t], acc);
            acc = fmaf(__sinf(d1 * fr), W1g[(DATA_DIM + f * 6 + 1) * MLP_W + t], acc);
            acc = fmaf(__sinf(d2 * fr), W1g[(DATA_DIM + f * 6 + 2) * MLP_W + t], acc);
            acc = fmaf(__cosf(d0 * fr), W1g[(DATA_DIM + f * 6 + 3) * MLP_W + t], acc);
            acc = fmaf(__cosf(d1 * fr), W1g[(DATA_DIM + f * 6 + 4) * MLP_W + t], acc);
            acc = fmaf(__cosf(d2 * fr), W1g[(DATA_DIM + f * 6 + 5) * MLP_W + t], acc);
        }
        pe_b1s[t] = acc;
    }
    __syncthreads();

    const int s = t;
    const bool lane_active = (s < NS);

    float i0 = tnear + (float)s * STEPF;
    float i1 = tnear + (float)(s + 1) * STEPF;
    float tm = 0.5f * (i0 + i1);
    float delta = (i1 - i0) * nrm;
    float px = o0 + d0 * tm, py = o1 + d1 * tm, pz = o2 + d2 * tm;
    bool m = lane_active && (tm < tmax) &&
             (fabsf(px) <= R) && (fabsf(py) <= R) && (fabsf(pz) <= R);

    float alpha = 0.0f, c0 = 0.0f, c1 = 0.0f, c2 = 0.0f;

    float x[DATA_DIM];
#pragma unroll
    for (int j = 0; j < DATA_DIM; ++j) x[j] = 0.0f;

    if (m) {
        float gx = (px / R + 1.0f) * (RESO * 0.5f);
        float gy = (py / R + 1.0f) * (RESO * 0.5f);
        float gz = (pz / R + 1.0f) * (RESO * 0.5f);
        float flx = floorf(gx), fly = floorf(gy), flz = floorf(gz);
        float ox = gx - flx, oy = gy - fly, oz = gz - flz;
        int ix = (int)flx, iy = (int)fly, iz = (int)flz;

#pragma unroll
        for (int n = 0; n < 8; ++n) {
            int bx = (n >> 2) & 1, by = (n >> 1) & 1, bz = n & 1;
            int cx = min(max(ix + bx, 0), RESO - 1);
            int cy = min(max(iy + by, 0), RESO - 1);
            int cz = min(max(iz + bz, 0), RESO - 1);
            uint32_t mi = morton3d((uint32_t)cx, (uint32_t)cy, (uint32_t)cz);
            float wv = (bx ? ox : 1.0f - ox) * (by ? oy : 1.0f - oy) * (bz ? oz : 1.0f - oz);

            // on-demand VQ: argmax of grid[mi, 0..15] (first-max-wins)
            const float4* g4 = (const float4*)(grid + ((size_t)mi << 4));
            float4 A = g4[0], B = g4[1], C = g4[2], D = g4[3];
            float v[16] = {A.x, A.y, A.z, A.w, B.x, B.y, B.z, B.w,
                           C.x, C.y, C.z, C.w, D.x, D.y, D.z, D.w};
            float bestv = v[0];
            int bi = 0;
#pragma unroll
            for (int j = 1; j < 16; ++j) {
                bi = (v[j] > bestv) ? j : bi;
                bestv = fmaxf(v[j], bestv);
            }

            const float4* cbr = (const float4*)&cbs[bi * DATA_DIM];
            float4 ca = cbr[0], cb4 = cbr[1], cc = cbr[2], cd = cbr[3];
            x[0]  = fmaf(wv, ca.x,  x[0]);  x[1]  = fmaf(wv, ca.y,  x[1]);
            x[2]  = fmaf(wv, ca.z,  x[2]);  x[3]  = fmaf(wv, ca.w,  x[3]);
            x[4]  = fmaf(wv, cb4.x, x[4]);  x[5]  = fmaf(wv, cb4.y, x[5]);
            x[6]  = fmaf(wv, cb4.z, x[6]);  x[7]  = fmaf(wv, cb4.w, x[7]);
            x[8]  = fmaf(wv, cc.x,  x[8]);  x[9]  = fmaf(wv, cc.y,  x[9]);
            x[10] = fmaf(wv, cc.z,  x[10]); x[11] = fmaf(wv, cc.w,  x[11]);
            x[12] = fmaf(wv, cd.x,  x[12]); x[13] = fmaf(wv, cd.y,  x[13]);
            x[14] = fmaf(wv, cd.z,  x[14]); x[15] = fmaf(wv, cd.w,  x[15]);
        }
    }

    // MLP under a wave-uniform guard so weight loads stay scalar (s_load)
    if (__any((int)m)) {
        float p0 = b2g[0], p1 = b2g[1], p2 = b2g[2], p3 = b2g[3];
#pragma unroll 4
        for (int o = 0; o < MLP_W; ++o) {
            float acc = pe_b1s[o];                                   // LDS broadcast
            const float4* wr = (const float4*)(W1dT + o * DATA_DIM); // uniform -> s_load
            float4 wa = wr[0], wb = wr[1], wc = wr[2], wd = wr[3];
            acc = fmaf(x[0],  wa.x, acc);  acc = fmaf(x[1],  wa.y, acc);
            acc = fmaf(x[2],  wa.z, acc);  acc = fmaf(x[3],  wa.w, acc);
            acc = fmaf(x[4],  wb.x, acc);  acc = fmaf(x[5],  wb.y, acc);
            acc = fmaf(x[6],  wb.z, acc);  acc = fmaf(x[7],  wb.w, acc);
            acc = fmaf(x[8],  wc.x, acc);  acc = fmaf(x[9],  wc.y, acc);
            acc = fmaf(x[10], wc.z, acc);  acc = fmaf(x[11], wc.w, acc);
            acc = fmaf(x[12], wd.x, acc);  acc = fmaf(x[13], wd.y, acc);
            acc = fmaf(x[14], wd.z, acc);  acc = fmaf(x[15], wd.w, acc);
            float h = fmaxf(acc, 0.0f);
            float4 w2 = *(const float4*)(W2g + o * 4);               // uniform -> s_load
            p0 = fmaf(h, w2.x, p0);
            p1 = fmaf(h, w2.y, p1);
            p2 = fmaf(h, w2.z, p2);
            p3 = fmaf(h, w2.w, p3);
        }
        if (m) {
            float dens = fmaxf(p0, 0.0f);
            alpha = 1.0f - __expf(-dens * delta);
            c0 = 1.0f / (1.0f + __expf(-p1));
            c1 = 1.0f / (1.0f + __expf(-p2));
            c2 = 1.0f / (1.0f + __expf(-p3));
        }
    }

    // ---- compositing: wave64 shuffle product-scan + cross-wave combine ----
    float inc = 1.0f - alpha + 1e-10f;
#pragma unroll
    for (int off = 1; off < 64; off <<= 1) {
        float u = __shfl_up(inc, off, 64);
        if (lane >= off) inc *= u;
    }
    float excl = __shfl_up(inc, 1, 64);
    if (lane == 0) excl = 1.0f;
    if (lane == 63) wtot[wid] = inc;   // wave total product
    __syncthreads();

    float wpre = 1.0f;                 // product of preceding waves
#pragma unroll
    for (int w = 0; w < NWAVES; ++w)
        if (w < wid) wpre *= wtot[w];
    float T = wpre * excl;
    float wgt = alpha * T;
    float r0 = wgt * c0, r1 = wgt * c1, r2 = wgt * c2, rw = wgt;

    if (lane_active) out_alpha[b * NS + s] = alpha;

    // ---- final rgb reduction ----
#pragma unroll
    for (int off = 32; off >= 1; off >>= 1) {
        r0 += __shfl_down(r0, off, 64);
        r1 += __shfl_down(r1, off, 64);
        r2 += __shfl_down(r2, off, 64);
        rw += __shfl_down(rw, off, 64);
    }
    if (lane == 0) { wred[wid][0] = r0; wred[wid][1] = r1; wred[wid][2] = r2; wred[wid][3] = rw; }
    __syncthreads();
    if (t == 0) {
        float s0 = 0, s1 = 0, s2 = 0, sw = 0;
#pragma unroll
        for (int i = 0; i < NWAVES; ++i) {
            s0 += wred[i][0]; s1 += wred[i][1]; s2 += wred[i][2]; sw += wred[i][3];
        }
        float bg = 1.0f - sw;
        out_rgb[b * 3 + 0] = s0 + bg;
        out_rgb[b * 3 + 1] = s1 + bg;
        out_rgb[b * 3 + 2] = s2 + bg;
    }
}

extern "C" void kernel_launch(void* const* d_in, const int* in_sizes, int n_in,
                              void* d_out, int out_size, void* d_ws, size_t ws_size,
                              hipStream_t stream) {
    const float* rays_o   = (const float*)d_in[0];
    const float* rays_d   = (const float*)d_in[1];
    const float* grid     = (const float*)d_in[2];
    const float* codebook = (const float*)d_in[3];
    const float* W1       = (const float*)d_in[4];
    const float* b1       = (const float*)d_in[5];
    const float* W2       = (const float*)d_in[6];
    const float* b2       = (const float*)d_in[7];
    float* out = (float*)d_out;

    float* W1dT = (float*)d_ws;   // 128*16 f32 = 8 KB

    w1_prep_kernel<<<1, 128, 0, stream>>>(W1, W1dT);
    nerf_main_kernel<<<BATCH, NT, 0, stream>>>(
        rays_o, rays_d, grid, codebook, W1, b1, W2, b2, W1dT,
        out /* rgb: 1024*3 */, out + BATCH * 3 /* alpha: 1024*442 */);
}